// Round 6
// baseline (5670.060 us; speedup 1.0000x reference)
//
#include <hip/hip_runtime.h>
#include <hip/hip_fp16.h>

// LSTM autoencoder B=256,S=512,D=64,H=128. 1 row/WG, 256 WGs, 1024 threads.
// Split-K lanes: L&1 = k-half, (L>>1)&3 = gate r (i,f,g,o), L>>3 = hidden j.
// Per-thread weights = 3 half-matrices = 24 h8 = 96 VGPRs (fits the 128 budget
// the allocator insists on; R3-R5 proved 192 is unimplementable).
// Half-combine via DPP xor1; gate gather via xor2 (quad_perm) + xor4 (ds_swizzle)
// + xor6 (xor2 of xor4). enc: 1 barrier/step; dec: 2 barriers/step.
// 4th matrix in LDS (enc: Wih0 + staged x row; dec: Whh1).
// fc projection: epilogue kernel, in-place in d_out.

typedef _Float16 h2 __attribute__((ext_vector_type(2)));
typedef _Float16 h8 __attribute__((ext_vector_type(8)));

#define Bsz 256
#define Ssz 512
#define Dsz 64
#define Hsz 128
#define NT 1024

__device__ __forceinline__ float fdot2f(h2 a, h2 b, float c) {
#if __has_builtin(__builtin_amdgcn_fdot2)
  return __builtin_amdgcn_fdot2(a, b, c, false);
#else
  return c + (float)a[0] * (float)b[0] + (float)a[1] * (float)b[1];
#endif
}

__device__ __forceinline__ float dot8(h8 v, h8 w, float acc) {
  h2 v0 = __builtin_shufflevector(v, v, 0, 1);
  h2 v1 = __builtin_shufflevector(v, v, 2, 3);
  h2 v2 = __builtin_shufflevector(v, v, 4, 5);
  h2 v3 = __builtin_shufflevector(v, v, 6, 7);
  h2 w0 = __builtin_shufflevector(w, w, 0, 1);
  h2 w1 = __builtin_shufflevector(w, w, 2, 3);
  h2 w2 = __builtin_shufflevector(w, w, 4, 5);
  h2 w3 = __builtin_shufflevector(w, w, 6, 7);
  acc = fdot2f(v0, w0, acc);
  acc = fdot2f(v1, w1, acc);
  acc = fdot2f(v2, w2, acc);
  acc = fdot2f(v3, w3, acc);
  return acc;
}

__device__ __forceinline__ float sigm(float v) { return 1.f / (1.f + __expf(-v)); }
__device__ __forceinline__ float tanh_f(float v) { return 2.f / (1.f + __expf(-2.f * v)) - 1.f; }

// quad_perm DPP: 0xB1=[1,0,3,2](xor1), 0x4E=[2,3,0,1](xor2)
template <int C, int M>
__device__ __forceinline__ float qperm(float x) {
#if __has_builtin(__builtin_amdgcn_mov_dpp)
  int i = __builtin_amdgcn_mov_dpp(__builtin_bit_cast(int, x), C, 0xf, 0xf, true);
  return __builtin_bit_cast(float, i);
#else
  return __shfl_xor(x, M, 64);
#endif
}

__device__ __forceinline__ float swz_xor4(float x) {
#if __has_builtin(__builtin_amdgcn_ds_swizzle)
  int i = __builtin_amdgcn_ds_swizzle(__builtin_bit_cast(int, x), 0x101F);
  return __builtin_bit_cast(float, i);
#else
  return __shfl_xor(x, 4, 64);
#endif
}

// lane L -> PyTorch gate-matrix row index
__device__ __forceinline__ int lcol(int L) { return (((L >> 1) & 3) << 7) + (L >> 3); }

__global__ void __launch_bounds__(NT, 4)
enc_kernel(const float* __restrict__ x,
           const h8* __restrict__ wih0, const h8* __restrict__ whh0,
           const h8* __restrict__ wih1, const h8* __restrict__ whh1,
           const float* __restrict__ b0v, const float* __restrict__ b1v,
           float* __restrict__ st) {
  __shared__ h8 s_wih0[4 * NT];        // 64 KiB
  __shared__ h8 sx[Ssz * 8];           // 64 KiB: whole x row as f16
  __shared__ h8 H0[2][16], H1[2][16];  // ~132 KiB total -> 1 WG/CU

  const int L = threadIdx.x;
  const int row = blockIdx.x;
  const int kb = (L & 1) << 3;         // k-half base (in h8 units of a 16-h8 col)
  const int r = (L >> 1) & 3;

  h8 Whh0r[8], Wih1r[8], Whh1r[8];     // 96 VGPRs of weights
#pragma unroll
  for (int k = 0; k < 8; ++k) Whh0r[k] = whh0[k * NT + L];
#pragma unroll
  for (int k = 0; k < 8; ++k) Wih1r[k] = wih1[k * NT + L];
#pragma unroll
  for (int k = 0; k < 8; ++k) Whh1r[k] = whh1[k * NT + L];
  for (int i = L; i < 4 * NT; i += NT) s_wih0[i] = wih0[i];
  {  // stage full x row -> f16 LDS
    const float* xr = x + (size_t)row * (Ssz * Dsz);
    _Float16* sxp = (_Float16*)sx;
    for (int e = L; e < Ssz * Dsz; e += NT) sxp[e] = (_Float16)xr[e];
  }
  if (L < 128) ((_Float16*)H0[0])[L] = (_Float16)0.f;
  else if (L < 256) ((_Float16*)H1[0])[L - 128] = (_Float16)0.f;

  const float b0 = b0v[L], b1 = b1v[L];  // pre-masked: odd lanes got 0
  const float Sc = (r == 2) ? 2.f : 1.f;
  const float Kc = (r == 2) ? 2.f : 1.f;
  const float Dc = (r == 2) ? -1.f : 0.f;
  float c0 = 0.f, c1 = 0.f;
  __syncthreads();

  for (int t = 0; t < Ssz; ++t) {
    const h8* H0r = H0[t & 1];
    h8* H0w = H0[(t + 1) & 1];
    // P1: layer0 gates (half-K per lane)
    float a = b0;
#pragma unroll
    for (int k = 0; k < 4; ++k) a = dot8(sx[t * 8 + (kb >> 1) + k], s_wih0[k * NT + L], a);
#pragma unroll
    for (int k = 0; k < 8; ++k) a = dot8(H0r[kb + k], Whh0r[k], a);
    a += qperm<0xB1, 1>(a);                       // combine k-halves
    float n = Sc * sigm(Kc * a) + Dc;
    float vf = qperm<0x4E, 2>(n);
    float vg = swz_xor4(n);
    float vo = qperm<0x4E, 2>(vg);
    if ((L & 7) == 0) {
      c0 = vf * c0 + n * vg;
      ((_Float16*)H0w)[L >> 3] = (_Float16)(vo * tanh_f(c0));
    }
    __syncthreads();
    // P2: layer1 gates
    const h8* H1r = H1[t & 1];
    h8* H1w = H1[(t + 1) & 1];
    float a1 = b1;
#pragma unroll
    for (int k = 0; k < 8; ++k) a1 = dot8(H0w[kb + k], Wih1r[k], a1);
#pragma unroll
    for (int k = 0; k < 8; ++k) a1 = dot8(H1r[kb + k], Whh1r[k], a1);
    a1 += qperm<0xB1, 1>(a1);
    n = Sc * sigm(Kc * a1) + Dc;
    vf = qperm<0x4E, 2>(n);
    vg = swz_xor4(n);
    vo = qperm<0x4E, 2>(vg);
    if ((L & 7) == 0) {
      c1 = vf * c1 + n * vg;
      ((_Float16*)H1w)[L >> 3] = (_Float16)(vo * tanh_f(c1));
    }
    // no barrier: next P1 reads only H0w (pre-barrier) and sx; H1w is read
    // by next P2, which is after next step's barrier.
  }
  __syncthreads();
  if ((L & 7) == 0) {
    int j = L >> 3;
    st[0 * Bsz * Hsz + row * Hsz + j] = (float)((_Float16*)H0[Ssz & 1])[j];
    st[1 * Bsz * Hsz + row * Hsz + j] = c0;
    st[2 * Bsz * Hsz + row * Hsz + j] = (float)((_Float16*)H1[Ssz & 1])[j];
    st[3 * Bsz * Hsz + row * Hsz + j] = c1;
  }
}

__global__ void __launch_bounds__(NT, 4)
dec_kernel(const h8* __restrict__ wprime, const h8* __restrict__ whh0,
           const h8* __restrict__ wih1, const h8* __restrict__ whh1,
           const float* __restrict__ b00v, const float* __restrict__ b0tv,
           const float* __restrict__ b1v, const float* __restrict__ st,
           _Float16* __restrict__ h1g) {
  __shared__ h8 s_whh1[8 * NT];        // 128 KiB -> 1 WG/CU
  __shared__ h8 H0[2][16], H1[2][16];

  const int L = threadIdx.x;
  const int row = blockIdx.x;
  const int kb = (L & 1) << 3;
  const int r = (L >> 1) & 3;

  h8 Wpr[8], Whh0r[8], Wih1r[8];       // 96 VGPRs of weights
#pragma unroll
  for (int k = 0; k < 8; ++k) Wpr[k] = wprime[k * NT + L];
#pragma unroll
  for (int k = 0; k < 8; ++k) Whh0r[k] = whh0[k * NT + L];
#pragma unroll
  for (int k = 0; k < 8; ++k) Wih1r[k] = wih1[k * NT + L];
  for (int i = L; i < 8 * NT; i += NT) s_whh1[i] = whh1[i];

  float c0 = 0.f, c1 = 0.f;
  if (L < 128)
    ((_Float16*)H0[0])[L] = (_Float16)st[0 * Bsz * Hsz + row * Hsz + L];
  else if (L < 256)
    ((_Float16*)H1[0])[L - 128] = (_Float16)st[2 * Bsz * Hsz + row * Hsz + (L - 128)];
  if ((L & 7) == 0) {
    c0 = st[1 * Bsz * Hsz + row * Hsz + (L >> 3)];
    c1 = st[3 * Bsz * Hsz + row * Hsz + (L >> 3)];
  }
  const float b00 = b00v[L], b0t = b0tv[L], b1 = b1v[L];  // pre-masked
  const float Sc = (r == 2) ? 2.f : 1.f;
  const float Kc = (r == 2) ? 2.f : 1.f;
  const float Dc = (r == 2) ? -1.f : 0.f;
  __syncthreads();

  for (int t = 0; t < Ssz; ++t) {
    const h8* H0r = H0[t & 1];
    h8* H0w = H0[(t + 1) & 1];
    const h8* H1r = H1[t & 1];         // h1(t-1): read once, feeds W' AND Whh1
    // P1: cell0 gates + Whh1 partial
    float a = (t > 0) ? b0t : b00;
    float a1 = b1;
    if (t > 0) {
#pragma unroll
      for (int k = 0; k < 8; ++k) {
        h8 hv = H1r[kb + k];
        a = dot8(hv, Wpr[k], a);                        // y(t-1)@Wih0 via W'
        a1 = dot8(hv, s_whh1[k * NT + L], a1);
      }
    } else {
#pragma unroll
      for (int k = 0; k < 8; ++k) a1 = dot8(H1r[kb + k], s_whh1[k * NT + L], a1);
    }
#pragma unroll
    for (int k = 0; k < 8; ++k) a = dot8(H0r[kb + k], Whh0r[k], a);
    a += qperm<0xB1, 1>(a);
    float n = Sc * sigm(Kc * a) + Dc;
    float vf = qperm<0x4E, 2>(n);
    float vg = swz_xor4(n);
    float vo = qperm<0x4E, 2>(vg);
    if ((L & 7) == 0) {
      c0 = vf * c0 + n * vg;
      ((_Float16*)H0w)[L >> 3] = (_Float16)(vo * tanh_f(c0));
    }
    __syncthreads();
    // P2: finish cell1 gates (a1 carried in reg across the barrier)
    h8* H1w = H1[(t + 1) & 1];
#pragma unroll
    for (int k = 0; k < 8; ++k) a1 = dot8(H0w[kb + k], Wih1r[k], a1);
    a1 += qperm<0xB1, 1>(a1);
    n = Sc * sigm(Kc * a1) + Dc;
    vf = qperm<0x4E, 2>(n);
    vg = swz_xor4(n);
    vo = qperm<0x4E, 2>(vg);
    if ((L & 7) == 0) {
      c1 = vf * c1 + n * vg;
      float h = vo * tanh_f(c1);
      ((_Float16*)H1w)[L >> 3] = (_Float16)h;
      h1g[((size_t)row * Ssz + t) * Hsz + (L >> 3)] = (_Float16)h;
    }
    __syncthreads();                   // next P1 reads H1w from all waves
  }
}

// Epilogue: out[rowt][j] = fcb[j] + h1[rowt].fcW[j]; in-place over d_out.
__global__ void __launch_bounds__(256)
out_kernel(const float* __restrict__ fcw, const float* __restrict__ fcb,
           float* __restrict__ out) {
  __shared__ h8 s_fc[64][17];
  __shared__ h8 s_h[64][16];
  const int tid = threadIdx.x;
  const size_t base = (size_t)blockIdx.x * 64;
  const h8* h1g = (const h8*)out;
#pragma unroll
  for (int i = 0; i < 4; ++i) {
    int idx = tid + 256 * i;
    s_h[idx >> 4][idx & 15] = h1g[base * 16 + idx];
  }
#pragma unroll
  for (int i = 0; i < 4; ++i) {
    int idx = tid + 256 * i;
    int jj = idx >> 4, k8 = idx & 15;
    h8 v;
#pragma unroll
    for (int e = 0; e < 8; ++e) v[e] = (_Float16)fcw[jj * 128 + k8 * 8 + e];
    s_fc[jj][k8] = v;
  }
  __syncthreads();
  const int j = tid & 63, rg = tid >> 6;
  const float bj = fcb[j];
#pragma unroll
  for (int i = 0; i < 16; ++i) {
    int rr = rg * 16 + i;
    float a0 = 0.f, a1 = 0.f;
#pragma unroll
    for (int k = 0; k < 16; k += 2) {
      a0 = dot8(s_h[rr][k], s_fc[j][k], a0);
      a1 = dot8(s_h[rr][k + 1], s_fc[j][k + 1], a1);
    }
    out[(base + rr) * 64 + j] = bj + a0 + a1;
  }
}

// ---- prep kernels ----

__device__ __forceinline__ int lcol_h(int L) { return (((L >> 1) & 3) << 7) + (L >> 3); }

// fp32 [512][K] -> h8 [K/16][1024]: o[kl*1024+L] = W[c(L)][(L&1)*K/2 + kl*8 ..+8]
__global__ void packp2_kernel(const float* __restrict__ W, h8* __restrict__ o, int K) {
  int idx = blockIdx.x * 256 + threadIdx.x;
  int tot = (K >> 4) * NT;
  if (idx >= tot) return;
  int kl = idx >> 10, L = idx & (NT - 1);
  const float* p = W + lcol_h(L) * K + (L & 1) * (K >> 1) + kl * 8;
  h8 v;
#pragma unroll
  for (int e = 0; e < 8; ++e) v[e] = (_Float16)p[e];
  o[idx] = v;
}

// W'[c][h] = sum_d Wih0_dec[c][d]*fcW[d][h]; packed [8][1024] like packp2(K=128)
__global__ void wprime2_kernel(const float* __restrict__ wih0d, const float* __restrict__ fcw,
                               h8* __restrict__ o) {
  int idx = blockIdx.x * 256 + threadIdx.x;
  if (idx >= 8 * NT) return;
  int kl = idx >> 10, L = idx & (NT - 1);
  int c = lcol_h(L);
  int hb = (L & 1) * 64 + kl * 8;
  h8 v;
#pragma unroll
  for (int e = 0; e < 8; ++e) {
    float s = 0.f;
    for (int d = 0; d < 64; ++d) s += wih0d[c * 64 + d] * fcw[d * 128 + hb + e];
    v[e] = (_Float16)s;
  }
  o[idx] = v;
}

// masked per-lane bias: o[L] = (L even) ? bih[c]+bhh[c] : 0
__global__ void biasp2_kernel(const float* __restrict__ a, const float* __restrict__ b,
                              float* __restrict__ o) {
  int L = blockIdx.x * 256 + threadIdx.x;
  if (L >= NT) return;
  int c = lcol_h(L);
  o[L] = (L & 1) ? 0.f : (a[c] + b[c]);
}

// o[L] = (L even) ? bih[c]+bhh[c] + sum_d fcb[d]*Wih0_dec[c][d] : 0
__global__ void bprime2_kernel(const float* __restrict__ a, const float* __restrict__ b,
                               const float* __restrict__ wih0d, const float* __restrict__ fcb,
                               float* __restrict__ o) {
  int L = blockIdx.x * 256 + threadIdx.x;
  if (L >= NT) return;
  int c = lcol_h(L);
  float s = a[c] + b[c];
  for (int d = 0; d < 64; ++d) s += fcb[d] * wih0d[c * 64 + d];
  o[L] = (L & 1) ? 0.f : s;
}

extern "C" void kernel_launch(void* const* d_in, const int* in_sizes, int n_in,
                              void* d_out, int out_size, void* d_ws, size_t ws_size,
                              hipStream_t stream) {
  (void)in_sizes; (void)n_in; (void)out_size; (void)ws_size;
  char* ws = (char*)d_ws;
  size_t off = 0;
  auto take = [&](size_t bytes) {
    char* p = ws + off;
    off += (bytes + 255) & ~(size_t)255;
    return p;
  };

  h8* e0_wih = (h8*)take(4 * NT * 16);
  h8* e0_whh = (h8*)take(8 * NT * 16);
  h8* e1_wih = (h8*)take(8 * NT * 16);
  h8* e1_whh = (h8*)take(8 * NT * 16);
  h8* d_wp   = (h8*)take(8 * NT * 16);
  h8* d0_whh = (h8*)take(8 * NT * 16);
  h8* d1_wih = (h8*)take(8 * NT * 16);
  h8* d1_whh = (h8*)take(8 * NT * 16);
  float* b_e0  = (float*)take(NT * 4);
  float* b_e1  = (float*)take(NT * 4);
  float* b_d00 = (float*)take(NT * 4);
  float* b_d0t = (float*)take(NT * 4);
  float* b_d1  = (float*)take(NT * 4);
  float* st    = (float*)take(4 * Bsz * Hsz * 4);

  const float* x = (const float*)d_in[0];

  packp2_kernel<<<16, 256, 0, stream>>>((const float*)d_in[1], e0_wih, 64);
  packp2_kernel<<<32, 256, 0, stream>>>((const float*)d_in[2], e0_whh, 128);
  packp2_kernel<<<32, 256, 0, stream>>>((const float*)d_in[5], e1_wih, 128);
  packp2_kernel<<<32, 256, 0, stream>>>((const float*)d_in[6], e1_whh, 128);
  wprime2_kernel<<<32, 256, 0, stream>>>((const float*)d_in[9], (const float*)d_in[17], d_wp);
  packp2_kernel<<<32, 256, 0, stream>>>((const float*)d_in[10], d0_whh, 128);
  packp2_kernel<<<32, 256, 0, stream>>>((const float*)d_in[13], d1_wih, 128);
  packp2_kernel<<<32, 256, 0, stream>>>((const float*)d_in[14], d1_whh, 128);

  biasp2_kernel<<<4, 256, 0, stream>>>((const float*)d_in[3], (const float*)d_in[4], b_e0);
  biasp2_kernel<<<4, 256, 0, stream>>>((const float*)d_in[7], (const float*)d_in[8], b_e1);
  biasp2_kernel<<<4, 256, 0, stream>>>((const float*)d_in[11], (const float*)d_in[12], b_d00);
  biasp2_kernel<<<4, 256, 0, stream>>>((const float*)d_in[15], (const float*)d_in[16], b_d1);
  bprime2_kernel<<<4, 256, 0, stream>>>((const float*)d_in[11], (const float*)d_in[12],
                                        (const float*)d_in[9], (const float*)d_in[18], b_d0t);

  enc_kernel<<<Bsz, NT, 0, stream>>>(x, e0_wih, e0_whh, e1_wih, e1_whh, b_e0, b_e1, st);
  dec_kernel<<<Bsz, NT, 0, stream>>>(d_wp, d0_whh, d1_wih, d1_whh,
                                     b_d00, b_d0t, b_d1, st, (_Float16*)d_out);
  out_kernel<<<(Bsz * Ssz) / 64, 256, 0, stream>>>((const float*)d_in[17],
                                                   (const float*)d_in[18], (float*)d_out);
}